// Round 2
// baseline (1036.910 us; speedup 1.0000x reference)
//
#include <hip/hip_runtime.h>
#include <math.h>

#define NN 50000
#define NE 800000
// DN=64, DE=32, H=4

// ---------------- transpose: dst[j*R+i] = src[i*C+j], src is R x C ----------
__global__ void k_transpose(const float* __restrict__ s, float* __restrict__ d, int R, int C){
  int idx = blockIdx.x * 256 + threadIdx.x;
  if (idx < R * C){
    int i = idx / C;
    int j = idx - i * C;
    d[j * R + i] = s[idx];
  }
}

// ---------------- node projections: p = relu(x @ W + b) ---------------------
// one thread per node, blockIdx.y selects projection (0=q,1=k,2=v)
// Wt is transposed [256][64] so inner loop reads contiguous uniform rows.
__global__ __launch_bounds__(256) void k_node_proj(
    const float* __restrict__ x,
    const float* __restrict__ wtq, const float* __restrict__ bq,
    const float* __restrict__ wtk, const float* __restrict__ bk,
    const float* __restrict__ wtv, const float* __restrict__ bv,
    float* __restrict__ pqk, float* __restrict__ pv){
  int n = blockIdx.x * 256 + threadIdx.x;
  if (n >= NN) return;
  int p = blockIdx.y;
  const float* wt = (p == 0) ? wtq : (p == 1) ? wtk : wtv;
  const float* bb = (p == 0) ? bq  : (p == 1) ? bk  : bv;
  float* out = (p == 0) ? pqk + (size_t)n * 512
             : (p == 1) ? pqk + (size_t)n * 512 + 256
                        : pv  + (size_t)n * 256;
  float xs[64];
  const float4* xv = (const float4*)(x + (size_t)n * 64);
  #pragma unroll
  for (int i = 0; i < 16; i++){
    float4 t = xv[i];
    xs[4*i+0] = t.x; xs[4*i+1] = t.y; xs[4*i+2] = t.z; xs[4*i+3] = t.w;
  }
  for (int j4 = 0; j4 < 64; j4++){
    const float* w0 = wt + (size_t)j4 * 256;  // 4 transposed rows of 64
    float a0 = bb[4*j4+0], a1 = bb[4*j4+1], a2 = bb[4*j4+2], a3 = bb[4*j4+3];
    #pragma unroll
    for (int c = 0; c < 64; c++){
      float xc = xs[c];
      a0 = fmaf(xc, w0[c],       a0);
      a1 = fmaf(xc, w0[64 + c],  a1);
      a2 = fmaf(xc, w0[128 + c], a2);
      a3 = fmaf(xc, w0[192 + c], a3);
    }
    float4 o = { fmaxf(a0, 0.f), fmaxf(a1, 0.f), fmaxf(a2, 0.f), fmaxf(a3, 0.f) };
    *(float4*)(out + 4 * j4) = o;
  }
}

// softmax over 4 values of s where s = min(exp(dot*inv_scale), 5)
// (reference: s = clip(exp(.), -5, 5); softmax(s) = exp(s-max)/sum)
__device__ __forceinline__ void attn_mix(const float* dots, float inv_scale, float* cg){
  cg[0] = cg[1] = cg[2] = cg[3] = 0.f;
  #pragma unroll
  for (int h = 0; h < 4; h++){
    float sv[4], mx = -1e30f;
    #pragma unroll
    for (int g = 0; g < 4; g++){
      sv[g] = fminf(expf(dots[h*4 + g] * inv_scale), 5.f);
      mx = fmaxf(mx, sv[g]);
    }
    float rs = 0.f;
    #pragma unroll
    for (int g = 0; g < 4; g++){ sv[g] = expf(sv[g] - mx); rs += sv[g]; }
    float ir = 1.f / rs;
    #pragma unroll
    for (int g = 0; g < 4; g++) cg[g] += sv[g] * ir;
  }
  #pragma unroll
  for (int g = 0; g < 4; g++) cg[g] *= 0.25f;
}

// ---------------- per-edge: gates, attention, value GEMV, output ------------
// one thread per edge. Also accumulates sigmoid gates + degree into per-node
// arrays via atomics (needed by node aggregation).
__global__ __launch_bounds__(256) void k_edge(
    const float* __restrict__ einp, const int* __restrict__ dstv,
    const float* __restrict__ qet, const float* __restrict__ qeb,
    const float* __restrict__ ket, const float* __restrict__ keb,
    const float* __restrict__ vet, const float* __restrict__ veb,
    float* __restrict__ wsum_q, float* __restrict__ wsum_k,
    int* __restrict__ counts, float* __restrict__ edge_out){
  int e = blockIdx.x * 256 + threadIdx.x;
  if (e >= NE) return;
  float es[32];
  const float4* ev4 = (const float4*)(einp + (size_t)e * 32);
  #pragma unroll
  for (int i = 0; i < 8; i++){
    float4 t = ev4[i];
    es[4*i+0] = t.x; es[4*i+1] = t.y; es[4*i+2] = t.z; es[4*i+3] = t.w;
  }
  // sigmoid gates (qe / ke projections), W transposed [4][32]
  float qw[4], kw[4];
  #pragma unroll
  for (int h = 0; h < 4; h++){
    float aq = qeb[h], ak = keb[h];
    #pragma unroll
    for (int c = 0; c < 32; c++){
      aq = fmaf(es[c], qet[h*32 + c], aq);
      ak = fmaf(es[c], ket[h*32 + c], ak);
    }
    qw[h] = 1.f / (1.f + expf(-aq));
    kw[h] = 1.f / (1.f + expf(-ak));
  }
  int d = dstv[e];
  #pragma unroll
  for (int h = 0; h < 4; h++){
    atomicAdd(&wsum_q[d*4 + h], qw[h]);
    atomicAdd(&wsum_k[d*4 + h], kw[h]);
  }
  atomicAdd(&counts[d], 1);
  // edge attention scores: dot = qw[h]*kw[g] (d-dim is 1)
  const float inv_scale = 0.17677669529663687f;  // 1/sqrt(32)
  float dots[16];
  #pragma unroll
  for (int h = 0; h < 4; h++)
    #pragma unroll
    for (int g = 0; g < 4; g++) dots[h*4 + g] = qw[h] * kw[g];
  float cg[4];
  attn_mix(dots, inv_scale, cg);
  // edge value GEMV + weighted mix; vet is transposed [128][32]
  float* outp = edge_out + (size_t)e * 32;
  for (int d4 = 0; d4 < 8; d4++){
    float o[4] = {0.f, 0.f, 0.f, 0.f};
    #pragma unroll
    for (int g = 0; g < 4; g++){
      #pragma unroll
      for (int dd = 0; dd < 4; dd++){
        int j = g * 32 + d4 * 4 + dd;
        float acc = veb[j];
        #pragma unroll
        for (int c = 0; c < 32; c++) acc = fmaf(es[c], vet[j*32 + c], acc);
        o[dd] = fmaf(cg[g], fmaxf(acc, 0.f), o[dd]);
      }
    }
    float4 ov = { o[0], o[1], o[2], o[3] };
    *(float4*)(outp + d4 * 4) = ov;
  }
}

// ---------------- CSR build: scan of per-dst counts -------------------------
__global__ __launch_bounds__(1024) void k_scan1(const int* __restrict__ counts,
                                                int* __restrict__ offsets,
                                                int* __restrict__ bsums){
  __shared__ int sd[1024];
  int tid = threadIdx.x;
  int gid = blockIdx.x * 1024 + tid;
  int v = (gid < NN) ? counts[gid] : 0;
  sd[tid] = v;
  __syncthreads();
  for (int off = 1; off < 1024; off <<= 1){
    int t = (tid >= off) ? sd[tid - off] : 0;
    __syncthreads();
    sd[tid] += t;
    __syncthreads();
  }
  int incl = sd[tid];
  if (gid < NN) offsets[gid] = incl - v;  // exclusive scan within block
  if (tid == 1023) bsums[blockIdx.x] = incl;
}

__global__ void k_scan2(int* __restrict__ bsums, int nb){
  int run = 0;
  for (int i = 0; i < nb; i++){ int t = bsums[i]; bsums[i] = run; run += t; }
}

__global__ __launch_bounds__(1024) void k_scan3(int* __restrict__ offsets,
                                                const int* __restrict__ bsums){
  int gid = blockIdx.x * 1024 + threadIdx.x;
  if (gid < NN) offsets[gid] += bsums[blockIdx.x];
  if (gid == 0) offsets[NN] = NE;
}

__global__ __launch_bounds__(256) void k_fill(const int* __restrict__ dstv,
                                              const int* __restrict__ offsets,
                                              int* __restrict__ cursor,
                                              int* __restrict__ csr){
  int e = blockIdx.x * 256 + threadIdx.x;
  if (e >= NE) return;
  int d = dstv[e];
  int pos = offsets[d] + atomicAdd(&cursor[d], 1);
  csr[pos] = e;
}

// ---------------- node aggregation + attention + output ---------------------
// one wave (64 lanes) per node; lane = d index
__global__ __launch_bounds__(256) void k_node_agg(
    const int* __restrict__ srcv, const int* __restrict__ offsets,
    const int* __restrict__ csr,
    const float* __restrict__ pqk, const float* __restrict__ pv,
    const float* __restrict__ wsum_q, const float* __restrict__ wsum_k,
    float* __restrict__ node_out){
  __shared__ float tile[4][512];
  int wid  = threadIdx.x >> 6;
  int lane = threadIdx.x & 63;
  int n = blockIdx.x * 4 + wid;           // NN divisible by 4
  int off0 = offsets[n], off1 = offsets[n + 1];
  float4 qa = {0.f,0.f,0.f,0.f}, ka = {0.f,0.f,0.f,0.f};
  int i = off0;
  int s_cur = 0;
  if (i < off1) s_cur = srcv[csr[i]];
  while (i < off1){
    int s_nxt = (i + 1 < off1) ? srcv[csr[i + 1]] : 0;   // prefetch scalar chain
    const float4* pr = (const float4*)(pqk + (size_t)s_cur * 512);
    float4 a = pr[lane];
    float4 b = pr[64 + lane];
    qa.x += a.x; qa.y += a.y; qa.z += a.z; qa.w += a.w;
    ka.x += b.x; ka.y += b.y; ka.z += b.z; ka.w += b.w;
    s_cur = s_nxt;
    i++;
  }
  // redistribute so each lane holds (h, d=lane) values
  float* tl = tile[wid];
  ((float4*)tl)[lane]      = qa;
  ((float4*)tl)[64 + lane] = ka;
  __syncthreads();
  float qh[4], kh[4];
  int deg = off1 - off0;
  if (deg > 0){
    float inv = 1.f / (float)deg;
    #pragma unroll
    for (int h = 0; h < 4; h++){
      qh[h] = (tl[h*64 + lane]       + wsum_q[n*4 + h]) * inv;
      kh[h] = (tl[256 + h*64 + lane] + wsum_k[n*4 + h]) * inv;
    }
  } else {
    #pragma unroll
    for (int h = 0; h < 4; h++){ qh[h] = 0.f; kh[h] = 0.f; }
  }
  // 16 dot products over 64 lanes via butterfly
  float dots[16];
  #pragma unroll
  for (int h = 0; h < 4; h++)
    #pragma unroll
    for (int g = 0; g < 4; g++) dots[h*4 + g] = qh[h] * kh[g];
  #pragma unroll
  for (int m = 1; m < 64; m <<= 1){
    #pragma unroll
    for (int t = 0; t < 16; t++) dots[t] += __shfl_xor(dots[t], m, 64);
  }
  const float inv_ns = 0.125f;  // 1/sqrt(64)
  float cg[4];
  attn_mix(dots, inv_ns, cg);
  const float* vb = pv + (size_t)n * 256;
  float o = 0.f;
  #pragma unroll
  for (int g = 0; g < 4; g++) o = fmaf(cg[g], vb[g*64 + lane], o);
  node_out[(size_t)n * 64 + lane] = o;
}

// ---------------------------------------------------------------------------
extern "C" void kernel_launch(void* const* d_in, const int* in_sizes, int n_in,
                              void* d_out, int out_size, void* d_ws, size_t ws_size,
                              hipStream_t stream) {
  const float* node_inputs = (const float*)d_in[0];
  const float* edge_inputs = (const float*)d_in[1];
  const int*   srcv        = (const int*)d_in[2];
  const int*   dstv        = (const int*)d_in[3];
  const float* qn_w = (const float*)d_in[4];
  const float* qn_b = (const float*)d_in[5];
  const float* qe_w = (const float*)d_in[6];
  const float* qe_b = (const float*)d_in[7];
  const float* kn_w = (const float*)d_in[8];
  const float* kn_b = (const float*)d_in[9];
  const float* ke_w = (const float*)d_in[10];
  const float* ke_b = (const float*)d_in[11];
  const float* vn_w = (const float*)d_in[12];
  const float* vn_b = (const float*)d_in[13];
  const float* ve_w = (const float*)d_in[14];
  const float* ve_b = (const float*)d_in[15];

  float* out      = (float*)d_out;
  float* node_out = out;                          // [NN,64]
  float* edge_out = out + (size_t)NN * 64;        // [NE,32]

  float* ws = (float*)d_ws;
  float* pqk    = ws;                              // 25,600,000 floats
  float* pv     = pqk + (size_t)NN * 512;          // 12,800,000
  float* wt_qn  = pv + (size_t)NN * 256;           // 16384
  float* wt_kn  = wt_qn + 16384;
  float* wt_vn  = wt_kn + 16384;
  float* wt_ve  = wt_vn + 16384;                   // 4096
  float* wt_qe  = wt_ve + 4096;                    // 128
  float* wt_ke  = wt_qe + 128;                     // 128
  float* wsum_q = wt_ke + 128;                     // 4*NN
  float* wsum_k = wsum_q + (size_t)4 * NN;         // 4*NN
  int* counts   = (int*)(wsum_k + (size_t)4 * NN); // NN
  int* cursor   = counts + NN;                     // NN
  int* offsets  = cursor + NN;                     // NN+1
  int* csr      = offsets + NN + 1;                // NE
  int* bsums    = csr + NE;                        // 64

  // zero wsum_q, wsum_k, counts, cursor (contiguous): 10*NN floats/ints
  hipMemsetAsync(wsum_q, 0, (size_t)10 * NN * sizeof(float), stream);

  // weight transposes
  k_transpose<<<(16384 + 255) / 256, 256, 0, stream>>>(qn_w, wt_qn, 64, 256);
  k_transpose<<<(16384 + 255) / 256, 256, 0, stream>>>(kn_w, wt_kn, 64, 256);
  k_transpose<<<(16384 + 255) / 256, 256, 0, stream>>>(vn_w, wt_vn, 64, 256);
  k_transpose<<<(4096  + 255) / 256, 256, 0, stream>>>(ve_w, wt_ve, 32, 128);
  k_transpose<<<1, 256, 0, stream>>>(qe_w, wt_qe, 32, 4);
  k_transpose<<<1, 256, 0, stream>>>(ke_w, wt_ke, 32, 4);

  // node projections (q,k,v)
  k_node_proj<<<dim3((NN + 255) / 256, 3), 256, 0, stream>>>(
      node_inputs, wt_qn, qn_b, wt_kn, kn_b, wt_vn, vn_b, pqk, pv);

  // per-edge everything (also histogram + gate sums)
  k_edge<<<NE / 256, 256, 0, stream>>>(
      edge_inputs, dstv, wt_qe, qe_b, wt_ke, ke_b, wt_ve, ve_b,
      wsum_q, wsum_k, counts, edge_out);

  // CSR build
  const int SB = (NN + 1023) / 1024;  // 49
  k_scan1<<<SB, 1024, 0, stream>>>(counts, offsets, bsums);
  k_scan2<<<1, 1, 0, stream>>>(bsums, SB);
  k_scan3<<<SB, 1024, 0, stream>>>(offsets, bsums);
  k_fill<<<NE / 256, 256, 0, stream>>>(dstv, offsets, cursor, csr);

  // node aggregation + attention + output
  k_node_agg<<<NN / 4, 256, 0, stream>>>(
      srcv, offsets, csr, pqk, pv, wsum_q, wsum_k, node_out);
}